// Round 1
// baseline (28903.366 us; speedup 1.0000x reference)
//
#include <hip/hip_runtime.h>
#include <cstdint>
#include <cstddef>

#define T_LEN 4096

typedef _Float16 half8 __attribute__((ext_vector_type(8)));
typedef _Float16 half4 __attribute__((ext_vector_type(4)));
typedef float floatx4 __attribute__((ext_vector_type(4)));
typedef unsigned long long u64;

#define MFMA16(a, b, c) __builtin_amdgcn_mfma_f32_16x16x32_f16((a), (b), (c), 0, 0, 0)
#define SCOPE_AGENT __HIP_MEMORY_SCOPE_AGENT

// ---- workspace layout (bytes) ----
static constexpr size_t OFF_W1  = 0;                          // [2048][576] f16  (k<64: w_ih1, k>=64: w_hh1)
static constexpr size_t SZ_W1   = (size_t)2048 * 576 * 2;
static constexpr size_t OFF_W2  = OFF_W1 + SZ_W1;             // [2048][1024] f16 (k<512: w_ih2, k>=512: w_hh2)
static constexpr size_t SZ_W2   = (size_t)2048 * 1024 * 2;
static constexpr size_t OFF_H12 = OFF_W2 + SZ_W2;             // [2][128][1024] f16 : [b][0:512]=h1, [512:1024]=h2
static constexpr size_t SZ_H12  = (size_t)2 * 128 * 1024 * 2;
static constexpr size_t OFF_B1  = OFF_H12 + SZ_H12;           // [2048] f32 combined bias layer1
static constexpr size_t OFF_B2  = OFF_B1 + 2048 * 4;          // [2048] f32 combined bias layer2
static constexpr size_t OFF_FLG = OFF_B2 + 2048 * 4;          // 512 ints: flag1[8][32], flag2[8][32]

__global__ void setup_kernel(const float* __restrict__ w_ih1, const float* __restrict__ w_hh1,
                             const float* __restrict__ b_ih1, const float* __restrict__ b_hh1,
                             const float* __restrict__ w_ih2, const float* __restrict__ w_hh2,
                             const float* __restrict__ b_ih2, const float* __restrict__ b_hh2,
                             _Float16* __restrict__ W1f, _Float16* __restrict__ W2f,
                             _Float16* __restrict__ h12, float* __restrict__ bias1,
                             float* __restrict__ bias2, int* __restrict__ flags)
{
  const int idx = blockIdx.x * blockDim.x + threadIdx.x;
  const int str = gridDim.x * blockDim.x;
  for (int i = idx; i < 2048 * 576; i += str) {
    const int r = i / 576, k = i - r * 576;
    const float v = (k < 64) ? w_ih1[r * 64 + k] : w_hh1[r * 512 + (k - 64)];
    W1f[i] = (_Float16)v;
  }
  for (int i = idx; i < 2048 * 1024; i += str) {
    const int r = i >> 10, k = i & 1023;
    const float v = (k < 512) ? w_ih2[r * 512 + k] : w_hh2[r * 512 + (k - 512)];
    W2f[i] = (_Float16)v;
  }
  for (int i = idx; i < 2 * 128 * 1024; i += str) h12[i] = (_Float16)0.0f;
  for (int i = idx; i < 2048; i += str) {
    bias1[i] = b_ih1[i] + b_hh1[i];
    bias2[i] = b_ih2[i] + b_hh2[i];
  }
  for (int i = idx; i < 512; i += str) flags[i] = 0;
}

__device__ __forceinline__ float sigm(float v) { return 1.0f / (1.0f + __expf(-v)); }
__device__ __forceinline__ float tanh_fast(float v) {
  v = fminf(fmaxf(v, -15.0f), 15.0f);
  const float e = __expf(2.0f * v);
  return (e - 1.0f) / (e + 1.0f);
}

__device__ __forceinline__ u64 ld_a_u64(const u64* p) {
  return __hip_atomic_load(p, __ATOMIC_RELAXED, SCOPE_AGENT);
}
__device__ __forceinline__ void st_a_u64(u64* p, u64 v) {
  __hip_atomic_store(p, v, __ATOMIC_RELAXED, SCOPE_AGENT);
}

// Grid: 256 WGs x 512 thr, cooperative. WG = (g = blockIdx%8 -> 16 batch rows, jj = blockIdx/8 -> 16 units).
// Superstep s: waves 0-3 gates1(s) [s<T]; waves 4-7 gates2(s-1) [1<=s<=T]; wave0 h1-ew+publish,
// wave1 h2-ew+publish, waves 2-3 y(s-2). Sync: per-WG release flags (no RMW counter),
// flag1[g][jj]=h1 steps published (critical), flag2=h2 steps (one superstep of slack).
// 2 barriers/superstep; hstage double-buffered; recurrent weights live in VGPRs.
__global__ __launch_bounds__(512, 1)
void lstm_kernel(const float* __restrict__ x,
                 const _Float16* __restrict__ W1f,
                 const _Float16* __restrict__ W2f,
                 const float* __restrict__ bias1,
                 const float* __restrict__ bias2,
                 const float* __restrict__ w_out,
                 const float* __restrict__ b_out,
                 _Float16* __restrict__ h12,
                 int* __restrict__ flags,
                 float* __restrict__ out)
{
  __shared__ __align__(16) _Float16 W2s[64 * 520];          // h1-half of W2 rows (gate*16+u), K 0..511
  __shared__ __align__(16) _Float16 hstage[2][2][16][520];  // [buf=s&1][0]=h1(s-1), [1]=h2(s-2)
  __shared__ float gbuf[2][4][16][20];                      // [layer][gate][unit n][batch m(+pad)]

  const int wg   = blockIdx.x;
  const int g    = wg & 7;
  const int jj   = wg >> 3;
  const int B0   = g * 16;
  const int U0   = jj * 16;
  const int tid  = threadIdx.x;
  const int lane = tid & 63;
  const int wv   = tid >> 6;
  const int lrow = lane & 15;
  const int quad = lane >> 4;

  int* f1 = flags + g * 32;          // flag1[g][jj]
  int* f2 = flags + 256 + g * 32;    // flag2[g][jj]
  u64* hb = (u64*)h12;

  // ---- stage h1-half of W2 into LDS (once) ----
  for (int c = tid; c < 64 * 128; c += 512) {
    const int r  = c >> 7;
    const int cc = c & 127;
    const int grow = ((r >> 4) << 9) + U0 + (r & 15);
    *(u64*)&W2s[r * 520 + cc * 4] = *(const u64*)&W2f[(size_t)grow * 1024 + cc * 4];
  }

  // ---- recurrent weights -> VGPRs (rows per lane are fixed for the whole sequence) ----
  half8 wreg[18];
  if (wv < 4) {
    const _Float16* wp = W1f + (size_t)((wv & 3) * 512 + U0 + lrow) * 576 + quad * 8;
#pragma unroll
    for (int kb = 0; kb < 18; ++kb) wreg[kb] = *(const half8*)(wp + kb * 32);
  } else {
    const _Float16* wp = W2f + (size_t)((wv & 3) * 512 + U0 + lrow) * 1024 + 512 + quad * 8;
#pragma unroll
    for (int kb = 0; kb < 16; ++kb) wreg[kb] = *(const half8*)(wp + kb * 32);
  }

  const _Float16* w2l = W2s + ((wv & 3) * 16 + lrow) * 520 + quad * 8;
  const float*    xrw = x + (size_t)(B0 + lrow) * (T_LEN * 64) + quad * 8;

  // cell state + bias (waves 0/1 only; 4 cells per lane: eb=lane&15, eu=(lane>>4)*4+j)
  float cst[4] = {0.f, 0.f, 0.f, 0.f};
  float bw[4][4];
  if (wv < 2) {
    const float* bsrc = (wv == 0) ? bias1 : bias2;
#pragma unroll
    for (int gg = 0; gg < 4; ++gg)
#pragma unroll
      for (int j = 0; j < 4; ++j) bw[gg][j] = bsrc[gg * 512 + U0 + (lane >> 4) * 4 + j];
  }
  float bo = 0.f;
  if (wv == 2 || wv == 3) bo = b_out[jj * 2 + (wv - 2)];

#pragma unroll 1
  for (int s = 0; s < T_LEN + 2; ++s) {
    const int p1 = s & 1;            // parity of h1(s); h1(s-1) at p1^1; h2(s-2) at p1
    const int sb = s & 1;            // hstage buffer

    // ---- x-part of gates1 BEFORE the wait (needs no staged data) ----
    floatx4 a0 = {0.f, 0.f, 0.f, 0.f};
    floatx4 a1 = {0.f, 0.f, 0.f, 0.f};
    if (wv < 4 && s < T_LEN) {
      const float* xr = xrw + (size_t)s * 64;
#pragma unroll
      for (int kb = 0; kb < 2; ++kb) {
        const floatx4 x0 = *(const floatx4*)(xr + kb * 32);
        const floatx4 x1 = *(const floatx4*)(xr + kb * 32 + 4);
        half8 av;
        av[0] = (_Float16)x0[0]; av[1] = (_Float16)x0[1];
        av[2] = (_Float16)x0[2]; av[3] = (_Float16)x0[3];
        av[4] = (_Float16)x1[0]; av[5] = (_Float16)x1[1];
        av[6] = (_Float16)x1[2]; av[7] = (_Float16)x1[3];
        if (kb & 1) a1 = MFMA16(av, wreg[kb], a1);
        else        a0 = MFMA16(av, wreg[kb], a0);
      }
    }

    // ---- distributed poll: lanes 0-31 -> flag1 >= s ; lanes 32-63 -> flag2 >= s-1 ----
    {
      int* fp = (lane < 32) ? (f1 + lane) : (f2 + (lane - 32));
      const int thr = (lane < 32) ? s : (s - 1);
      while (!__all(__hip_atomic_load(fp, __ATOMIC_RELAXED, SCOPE_AGENT) >= thr))
        __builtin_amdgcn_s_sleep(1);
      asm volatile("" ::: "memory");
    }

    // ---- stage h-state into hstage[sb] ----
    {
      const u64* h1src = hb + (size_t)(p1 ^ 1) * 32768;
      const u64* h2src = hb + (size_t)p1 * 32768;
#pragma unroll
      for (int i = 0; i < 8; ++i) {
        const int idx  = tid + i * 512;        // 0..4095
        const int half = idx >> 11;
        const int r    = (idx >> 7) & 15;
        const int cc   = idx & 127;
        u64 v;
        if (half == 0) v = ld_a_u64(h1src + (size_t)(B0 + r) * 256 + cc);
        else           v = ld_a_u64(h2src + (size_t)(B0 + r) * 256 + 128 + cc);
        *(u64*)&hstage[sb][half][r][cc * 4] = v;
      }
    }
    __syncthreads();                           // B: staging done

    // ---- MFMA phase ----
    if (wv < 4) {
      if (s < T_LEN) {
#pragma unroll
        for (int kb = 2; kb < 18; ++kb) {
          const half8 av = *(const half8*)(&hstage[sb][0][lrow][(kb - 2) * 32 + quad * 8]);
          if (kb & 1) a1 = MFMA16(av, wreg[kb], a1);
          else        a0 = MFMA16(av, wreg[kb], a0);
        }
        const floatx4 a = a0 + a1;
        *(floatx4*)(&gbuf[0][wv][lrow][quad * 4]) = a;
      }
    } else {
      if (s >= 1 && s <= T_LEN) {
#pragma unroll
        for (int kb = 0; kb < 16; ++kb) {      // h1(s-1) x W2s(LDS)
          const half8 av = *(const half8*)(&hstage[sb][0][lrow][kb * 32 + quad * 8]);
          const half8 bv = *(const half8*)(w2l + kb * 32);
          if (kb & 1) a1 = MFMA16(av, bv, a1);
          else        a0 = MFMA16(av, bv, a0);
        }
#pragma unroll
        for (int kb = 0; kb < 16; ++kb) {      // h2(s-2) x W2 h2-half (registers)
          const half8 av = *(const half8*)(&hstage[sb][1][lrow][kb * 32 + quad * 8]);
          if (kb & 1) a1 = MFMA16(av, wreg[kb], a1);
          else        a0 = MFMA16(av, wreg[kb], a0);
        }
        const floatx4 a = a0 + a1;
        *(floatx4*)(&gbuf[1][wv & 3][lrow][quad * 4]) = a;
      }
    }
    __syncthreads();                           // C: gates ready

    // ---- elementwise + publish (early release) ----
    if (wv == 0) {
      if (s < T_LEN) {                         // h1(s): 4 cells/lane, one u64 store
        const int eb = lane & 15, qq = lane >> 4;
        union { half4 h; u64 u; } pk;
#pragma unroll
        for (int j = 0; j < 4; ++j) {
          const int eu = qq * 4 + j;
          const float s0 = gbuf[0][0][eu][eb] + bw[0][j];
          const float s1 = gbuf[0][1][eu][eb] + bw[1][j];
          const float s2 = gbuf[0][2][eu][eb] + bw[2][j];
          const float s3 = gbuf[0][3][eu][eb] + bw[3][j];
          const float iv = sigm(s0), fv = sigm(s1);
          const float gv = tanh_fast(s2), ov = sigm(s3);
          cst[j] = fv * cst[j] + iv * gv;
          pk.h[j] = (_Float16)(ov * tanh_fast(cst[j]));
        }
        st_a_u64(hb + (size_t)p1 * 32768 + (size_t)(B0 + eb) * 256 + (U0 >> 2) + qq, pk.u);
      }
      if (s <= T_LEN) {
        asm volatile("s_waitcnt vmcnt(0)" ::: "memory");   // h1 stores acked before flag
        if (lane == 0)
          __hip_atomic_store(&f1[jj], s + 1, __ATOMIC_RELAXED, SCOPE_AGENT);
      }
    } else if (wv == 1) {
      if (s >= 1 && s <= T_LEN) {              // h2(s-1)
        const int eb = lane & 15, qq = lane >> 4;
        union { half4 h; u64 u; } pk;
#pragma unroll
        for (int j = 0; j < 4; ++j) {
          const int eu = qq * 4 + j;
          const float s0 = gbuf[1][0][eu][eb] + bw[0][j];
          const float s1 = gbuf[1][1][eu][eb] + bw[1][j];
          const float s2 = gbuf[1][2][eu][eb] + bw[2][j];
          const float s3 = gbuf[1][3][eu][eb] + bw[3][j];
          const float iv = sigm(s0), fv = sigm(s1);
          const float gv = tanh_fast(s2), ov = sigm(s3);
          cst[j] = fv * cst[j] + iv * gv;
          pk.h[j] = (_Float16)(ov * tanh_fast(cst[j]));
        }
        st_a_u64(hb + (size_t)(p1 ^ 1) * 32768 + (size_t)(B0 + eb) * 256 + 128 + (U0 >> 2) + qq, pk.u);
        asm volatile("s_waitcnt vmcnt(0)" ::: "memory");
        if (lane == 0)
          __hip_atomic_store(&f2[jj], s, __ATOMIC_RELAXED, SCOPE_AGENT);
      }
    } else if (wv < 4) {
      if (s >= 2) {                            // y(s-2): 16 dots/wave, 4 lanes/dot, shfl reduce
        const int b  = lane >> 2;
        const int kp = lane & 3;
        const int oi = jj * 2 + (wv - 2);
        const float* wr = w_out + oi * 512 + kp * 128;
        float sacc = 0.f;
#pragma unroll
        for (int kc = 0; kc < 16; ++kc) {
          const half8  hv8 = *(const half8*)(&hstage[sb][1][b][kp * 128 + kc * 8]);
          const floatx4 w0 = *(const floatx4*)(wr + kc * 8);
          const floatx4 w1 = *(const floatx4*)(wr + kc * 8 + 4);
          sacc += (float)hv8[0] * w0[0] + (float)hv8[1] * w0[1]
                + (float)hv8[2] * w0[2] + (float)hv8[3] * w0[3]
                + (float)hv8[4] * w1[0] + (float)hv8[5] * w1[1]
                + (float)hv8[6] * w1[2] + (float)hv8[7] * w1[3];
        }
        sacc += __shfl_xor(sacc, 1);
        sacc += __shfl_xor(sacc, 2);
        if (kp == 0)
          out[((size_t)(B0 + b) * T_LEN + (s - 2)) * 64 + oi] = sacc + bo;
      }
    }
    // no end-of-loop barrier: hstage double-buffered; gbuf reuse guarded by barrier B of s+1
  }
}

extern "C" void kernel_launch(void* const* d_in, const int* in_sizes, int n_in,
                              void* d_out, int out_size, void* d_ws, size_t ws_size,
                              hipStream_t stream) {
  (void)in_sizes; (void)n_in; (void)out_size; (void)ws_size;

  const float* x      = (const float*)d_in[0];
  const float* w_ih1  = (const float*)d_in[1];
  const float* w_hh1  = (const float*)d_in[2];
  const float* b_ih1  = (const float*)d_in[3];
  const float* b_hh1  = (const float*)d_in[4];
  const float* w_ih2  = (const float*)d_in[5];
  const float* w_hh2  = (const float*)d_in[6];
  const float* b_ih2  = (const float*)d_in[7];
  const float* b_hh2  = (const float*)d_in[8];
  const float* w_out  = (const float*)d_in[9];
  const float* b_out  = (const float*)d_in[10];

  char* ws = (char*)d_ws;
  _Float16* W1f   = (_Float16*)(ws + OFF_W1);
  _Float16* W2f   = (_Float16*)(ws + OFF_W2);
  _Float16* h12   = (_Float16*)(ws + OFF_H12);
  float*    bias1 = (float*)(ws + OFF_B1);
  float*    bias2 = (float*)(ws + OFF_B2);
  int*      flags = (int*)(ws + OFF_FLG);
  float*    outp  = (float*)d_out;

  hipLaunchKernelGGL(setup_kernel, dim3(1024), dim3(256), 0, stream,
                     w_ih1, w_hh1, b_ih1, b_hh1, w_ih2, w_hh2, b_ih2, b_hh2,
                     W1f, W2f, h12, bias1, bias2, flags);

  void* args[] = { (void*)&x, (void*)&W1f, (void*)&W2f, (void*)&bias1, (void*)&bias2,
                   (void*)&w_out, (void*)&b_out, (void*)&h12, (void*)&flags, (void*)&outp };
  hipLaunchCooperativeKernel((void*)lstm_kernel, dim3(256), dim3(512), args, 0, stream);
}